// Round 1
// baseline (893.974 us; speedup 1.0000x reference)
//
#include <hip/hip_runtime.h>
#include <hip/hip_bf16.h>
#include <stdint.h>

typedef __attribute__((ext_vector_type(8))) short bf16x8;
typedef __attribute__((ext_vector_type(4))) float f32x4;

#define B_   2
#define SQ_  2048
#define H_   4096
#define NH_  32
#define NG_  2
#define HN_  128
#define QKVO 4608

__device__ __forceinline__ unsigned short f2b(float f) {
    union { float f; uint32_t u; } v; v.f = f;
    uint32_t u = v.u;
    u += 0x7FFFu + ((u >> 16) & 1u);   // round-to-nearest-even
    return (unsigned short)(u >> 16);
}
__device__ __forceinline__ float b2f(unsigned short h) {
    union { uint32_t u; float f; } v; v.u = ((uint32_t)h) << 16;
    return v.f;
}

// ---------------- f32 -> bf16 convert (memory-bound, float4 vectorized) ----------------
__global__ __launch_bounds__(256) void cvt_kernel(const float* __restrict__ in,
                                                  unsigned short* __restrict__ out,
                                                  int n) {
    int i = (blockIdx.x * 256 + threadIdx.x) * 4;
    if (i >= n) return;
    float4 v = *reinterpret_cast<const float4*>(in + i);
    ushort4 o;
    o.x = f2b(v.x); o.y = f2b(v.y); o.z = f2b(v.z); o.w = f2b(v.w);
    *reinterpret_cast<ushort4*>(out + i) = o;
}

// ---------------- m97-structure bf16 GEMM: C = A @ B^T (+bias) ----------------
// A [M][K] bf16 row-major, B [N][K] bf16 row-major (K contiguous both sides).
#define GLD16(gp, lp) \
  __builtin_amdgcn_global_load_lds((const __attribute__((address_space(1))) void*)(gp), \
                                   (__attribute__((address_space(3))) void*)(lp), 16, 0, 0)

template<int OUT_BF16, int HAS_BIAS>
__global__ __launch_bounds__(256) void gemm_bt(const unsigned short* __restrict__ A,
                                               const unsigned short* __restrict__ Bm,
                                               const float* __restrict__ bias,
                                               void* __restrict__ C,
                                               int M, int N, int K) {
    __shared__ unsigned short As[128 * 32];
    __shared__ unsigned short Bs[128 * 32];
    const int tid = threadIdx.x;
    const int wave = tid >> 6, lane = tid & 63;
    const int lr = lane & 15, lg = lane >> 4;
    const int m0 = blockIdx.x * 128, n0 = blockIdx.y * 128;
    const int wr = wave >> 1, wc = wave & 1;

    const int srow = lane >> 2;        // 0..15 within chunk
    const int skk  = (lane & 3) * 8;   // 0,8,16,24

    f32x4 acc[4][4] = {};

    for (int k0 = 0; k0 < K; k0 += 32) {
        __syncthreads();
        #pragma unroll
        for (int c = 0; c < 2; ++c) {
            int ch = c * 4 + wave;            // 8 chunks of 512 elems
            int row = ch * 16 + srow;
            GLD16(A  + (size_t)(m0 + row) * K + k0 + skk, As + ch * 512);
            GLD16(Bm + (size_t)(n0 + row) * K + k0 + skk, Bs + ch * 512);
        }
        __syncthreads();   // compiler drains vmcnt here
        bf16x8 af[4], bf[4];
        #pragma unroll
        for (int i = 0; i < 4; ++i)
            af[i] = *reinterpret_cast<const bf16x8*>(As + (wr * 64 + i * 16 + lr) * 32 + lg * 8);
        #pragma unroll
        for (int j = 0; j < 4; ++j)
            bf[j] = *reinterpret_cast<const bf16x8*>(Bs + (wc * 64 + j * 16 + lr) * 32 + lg * 8);
        #pragma unroll
        for (int i = 0; i < 4; ++i)
            #pragma unroll
            for (int j = 0; j < 4; ++j)
                acc[i][j] = __builtin_amdgcn_mfma_f32_16x16x32_bf16(af[i], bf[j], acc[i][j], 0, 0, 0);
    }

    const int crow0 = m0 + wr * 64;
    const int ccol0 = n0 + wc * 64;
    #pragma unroll
    for (int j = 0; j < 4; ++j) {
        int col = ccol0 + j * 16 + lr;
        float bv = 0.f;
        if (HAS_BIAS) bv = bias[col];
        #pragma unroll
        for (int i = 0; i < 4; ++i) {
            #pragma unroll
            for (int r = 0; r < 4; ++r) {
                int row = crow0 + i * 16 + lg * 4 + r;   // D: col=lane&15, row=(lane>>4)*4+reg
                float vv = acc[i][j][r] + bv;
                if (OUT_BF16)
                    reinterpret_cast<unsigned short*>(C)[(size_t)row * N + col] = f2b(vv);
                else
                    reinterpret_cast<float*>(C)[(size_t)row * N + col] = vv;
            }
        }
    }
}

// ---------------- RoPE + GQA scatter ----------------
// mixed [b*sq][4608] bf16 -> q [b][32][sq][128], k/v [b][2][sq][128] bf16
__global__ __launch_bounds__(256) void rope_scatter(const unsigned short* __restrict__ mixed,
                                                    const float* __restrict__ cache,
                                                    unsigned short* __restrict__ q,
                                                    unsigned short* __restrict__ k,
                                                    unsigned short* __restrict__ v) {
    int idx = blockIdx.x * 256 + threadIdx.x;   // one 8-elem chunk per thread
    int c = idx & 15;
    int t = idx >> 4;
    int head = t % 36;
    int bs = t / 36;             // batch*2048 + s
    int s = bs & 2047;
    int batch = bs >> 11;

    const unsigned short* src = mixed + (size_t)bs * QKVO + head * 128 + c * 8;
    bf16x8 xv = *reinterpret_cast<const bf16x8*>(src);
    float x[8];
    #pragma unroll
    for (int j = 0; j < 8; ++j) x[j] = b2f((unsigned short)xv[j]);

    if (head < 34 && c < 8) {   // rope on q,k first 64 dims; interleaved pairs
        const float* cp = cache + ((size_t)s * 32 + c * 4) * 2;
        #pragma unroll
        for (int jj = 0; jj < 4; ++jj) {
            float co = cp[jj * 2 + 0], si = cp[jj * 2 + 1];
            float x0 = x[2 * jj], x1 = x[2 * jj + 1];
            x[2 * jj]     = x0 * co - x1 * si;
            x[2 * jj + 1] = x1 * co + x0 * si;
        }
    }
    bf16x8 ov;
    #pragma unroll
    for (int j = 0; j < 8; ++j) ov[j] = (short)f2b(x[j]);

    unsigned short* dst;
    if (head < 32)
        dst = q + (((size_t)(batch * NH_ + head) * SQ_ + s) * HN_) + c * 8;
    else if (head < 34)
        dst = k + (((size_t)(batch * NG_ + (head - 32)) * SQ_ + s) * HN_) + c * 8;
    else
        dst = v + (((size_t)(batch * NG_ + (head - 34)) * SQ_ + s) * HN_) + c * 8;
    *reinterpret_cast<bf16x8*>(dst) = ov;
}

// ---------------- causal GQA flash attention ----------------
// grid (b*NH, sq/128); 256 threads = 4 waves, wave owns 32 q-rows.
__global__ __launch_bounds__(256) void attn_kernel(const unsigned short* __restrict__ Q,
                                                   const unsigned short* __restrict__ K,
                                                   const unsigned short* __restrict__ V,
                                                   unsigned short* __restrict__ ctx) {
    __shared__ unsigned short Kl[64 * 136];   // [key][d] padded (+8) -> 2-way-free reads
    __shared__ unsigned short Vt[128 * 72];   // [d][key] transposed, padded
    __shared__ unsigned short Pl[128 * 72];   // [q][key] padded, wave-local round-trip

    const int bh = blockIdx.x;
    const int qt = blockIdx.y;
    const int batch = bh >> 5, h = bh & 31, g = h >> 4;   // GQA: 16 q-heads per kv-group
    const int tid = threadIdx.x, wave = tid >> 6, lane = tid & 63;
    const int lr = lane & 15, lg = lane >> 4;
    const int q0 = qt * 128;

    const unsigned short* Qp = Q + ((size_t)(batch * NH_ + h) * SQ_ + q0 + wave * 32) * HN_;
    const unsigned short* Kp = K + (size_t)(batch * NG_ + g) * SQ_ * HN_;
    const unsigned short* Vp = V + (size_t)(batch * NG_ + g) * SQ_ * HN_;

    bf16x8 qf[2][4];   // Q resident in regs: [mi][kd]
    #pragma unroll
    for (int mi = 0; mi < 2; ++mi)
        #pragma unroll
        for (int kd = 0; kd < 4; ++kd)
            qf[mi][kd] = *reinterpret_cast<const bf16x8*>(Qp + (size_t)(mi * 16 + lr) * HN_ + kd * 32 + lg * 8);

    f32x4 ctxa[2][8] = {};
    float mrow[2][4], lsum[2][4];
    #pragma unroll
    for (int mi = 0; mi < 2; ++mi)
        #pragma unroll
        for (int r = 0; r < 4; ++r) { mrow[mi][r] = -1e30f; lsum[mi][r] = 0.f; }

    const float scale = 0.088388347648318447f;   // 1/sqrt(128)
    const float LOG2E = 1.4426950408889634f;

    const int nkt = (q0 + 128) / 64;
    for (int kt = 0; kt < nkt; ++kt) {
        const int kbase = kt * 64;
        __syncthreads();
        #pragma unroll
        for (int it = 0; it < 4; ++it) {      // stage K tile + transposed V tile
            int idx = it * 256 + tid;
            int row = idx >> 4;               // key 0..63
            int cc = (idx & 15) * 8;          // d chunk
            bf16x8 kv = *reinterpret_cast<const bf16x8*>(Kp + (size_t)(kbase + row) * HN_ + cc);
            *reinterpret_cast<bf16x8*>(Kl + row * 136 + cc) = kv;
            bf16x8 vv = *reinterpret_cast<const bf16x8*>(Vp + (size_t)(kbase + row) * HN_ + cc);
            #pragma unroll
            for (int j = 0; j < 8; ++j)
                Vt[(cc + j) * 72 + row] = (unsigned short)vv[j];
        }
        __syncthreads();

        // S = Q K^T  (A=Q frags, B=K rows read K-contiguous)
        f32x4 s[2][4] = {};
        #pragma unroll
        for (int kf = 0; kf < 4; ++kf) {
            #pragma unroll
            for (int kd = 0; kd < 4; ++kd) {
                bf16x8 kfrag = *reinterpret_cast<const bf16x8*>(Kl + (kf * 16 + lr) * 136 + kd * 32 + lg * 8);
                #pragma unroll
                for (int mi = 0; mi < 2; ++mi)
                    s[mi][kf] = __builtin_amdgcn_mfma_f32_16x16x32_bf16(qf[mi][kd], kfrag, s[mi][kf], 0, 0, 0);
            }
        }

        // scale + causal mask (keep k <= q)
        #pragma unroll
        for (int mi = 0; mi < 2; ++mi)
            #pragma unroll
            for (int kf = 0; kf < 4; ++kf)
                #pragma unroll
                for (int r = 0; r < 4; ++r) {
                    int qrow = q0 + wave * 32 + mi * 16 + lg * 4 + r;
                    int kcol = kbase + kf * 16 + lr;
                    float xv = s[mi][kf][r] * scale;
                    s[mi][kf][r] = (kcol <= qrow) ? xv : -1e30f;
                }

        // online softmax per q-row (row lives across 16 lanes of the lg-group)
        #pragma unroll
        for (int mi = 0; mi < 2; ++mi) {
            #pragma unroll
            for (int r = 0; r < 4; ++r) {
                float pm = fmaxf(fmaxf(s[mi][0][r], s[mi][1][r]), fmaxf(s[mi][2][r], s[mi][3][r]));
                pm = fmaxf(pm, __shfl_xor(pm, 1));
                pm = fmaxf(pm, __shfl_xor(pm, 2));
                pm = fmaxf(pm, __shfl_xor(pm, 4));
                pm = fmaxf(pm, __shfl_xor(pm, 8));
                float mnew = fmaxf(mrow[mi][r], pm);
                float resc = exp2f((mrow[mi][r] - mnew) * LOG2E);
                float ps = 0.f;
                #pragma unroll
                for (int kf = 0; kf < 4; ++kf) {
                    float p = exp2f((s[mi][kf][r] - mnew) * LOG2E);
                    s[mi][kf][r] = p;
                    ps += p;
                }
                ps += __shfl_xor(ps, 1);
                ps += __shfl_xor(ps, 2);
                ps += __shfl_xor(ps, 4);
                ps += __shfl_xor(ps, 8);
                lsum[mi][r] = lsum[mi][r] * resc + ps;
                mrow[mi][r] = mnew;
                #pragma unroll
                for (int df = 0; df < 8; ++df)
                    ctxa[mi][df][r] *= resc;
                #pragma unroll
                for (int kf = 0; kf < 4; ++kf)
                    Pl[(wave * 32 + mi * 16 + lg * 4 + r) * 72 + kf * 16 + lr] = f2b(s[mi][kf][r]);
            }
        }
        asm volatile("s_waitcnt lgkmcnt(0)" ::: "memory");   // wave-local P round-trip

        // ctx += P @ V   (A=P from LDS, B=V^T rows read key-contiguous)
        #pragma unroll
        for (int ks = 0; ks < 2; ++ks) {
            bf16x8 pfrag[2];
            #pragma unroll
            for (int mi = 0; mi < 2; ++mi)
                pfrag[mi] = *reinterpret_cast<const bf16x8*>(Pl + (wave * 32 + mi * 16 + lr) * 72 + ks * 32 + lg * 8);
            #pragma unroll
            for (int df = 0; df < 8; ++df) {
                bf16x8 vfrag = *reinterpret_cast<const bf16x8*>(Vt + (df * 16 + lr) * 72 + ks * 32 + lg * 8);
                #pragma unroll
                for (int mi = 0; mi < 2; ++mi)
                    ctxa[mi][df] = __builtin_amdgcn_mfma_f32_16x16x32_bf16(pfrag[mi], vfrag, ctxa[mi][df], 0, 0, 0);
            }
        }
    }

    // finalize: ctx /= l, write bf16 [b*sq][4096] (head-major cols)
    #pragma unroll
    for (int mi = 0; mi < 2; ++mi) {
        #pragma unroll
        for (int r = 0; r < 4; ++r) {
            float inv = 1.f / lsum[mi][r];
            int row = batch * SQ_ + q0 + wave * 32 + mi * 16 + lg * 4 + r;
            #pragma unroll
            for (int df = 0; df < 8; ++df) {
                int col = h * HN_ + df * 16 + lr;
                ctx[(size_t)row * (NH_ * HN_) + col] = f2b(ctxa[mi][df][r] * inv);
            }
        }
    }
}

extern "C" void kernel_launch(void* const* d_in, const int* in_sizes, int n_in,
                              void* d_out, int out_size, void* d_ws, size_t ws_size,
                              hipStream_t stream) {
    const float* hs      = (const float*)d_in[0];
    const float* cache   = (const float*)d_in[1];
    const float* w_qkv   = (const float*)d_in[2];
    const float* b_qkv   = (const float*)d_in[3];
    const float* w_dense = (const float*)d_in[4];
    float* out = (float*)d_out;

    char* p = (char*)d_ws;
    unsigned short* hs_b    = (unsigned short*)p; p += (size_t)16777216 * 2;  // [4096][4096]
    unsigned short* wqkv_b  = (unsigned short*)p; p += (size_t)18874368 * 2;  // [4608][4096]
    unsigned short* wd_b    = (unsigned short*)p; p += (size_t)16777216 * 2;  // [4096][4096]
    unsigned short* mixed_b = (unsigned short*)p; p += (size_t)18874368 * 2;  // [4096][4608]
    unsigned short* q_b     = (unsigned short*)p; p += (size_t)16777216 * 2;  // [2][32][2048][128]
    unsigned short* k_b     = (unsigned short*)p; p += (size_t)1048576 * 2;   // [2][2][2048][128]
    unsigned short* v_b     = (unsigned short*)p; p += (size_t)1048576 * 2;
    unsigned short* ctx_b   = (unsigned short*)p; p += (size_t)16777216 * 2;  // [4096][4096]

    cvt_kernel<<<16384, 256, 0, stream>>>(hs, hs_b, 16777216);
    cvt_kernel<<<18432, 256, 0, stream>>>(w_qkv, wqkv_b, 18874368);
    cvt_kernel<<<16384, 256, 0, stream>>>(w_dense, wd_b, 16777216);

    dim3 g1(32, 36);
    gemm_bt<1, 1><<<g1, 256, 0, stream>>>(hs_b, wqkv_b, b_qkv, (void*)mixed_b, 4096, 4608, 4096);

    rope_scatter<<<9216, 256, 0, stream>>>(mixed_b, cache, q_b, k_b, v_b);

    dim3 g2(64, 16);
    attn_kernel<<<g2, 256, 0, stream>>>(q_b, k_b, v_b, ctx_b);

    dim3 g3(32, 32);
    gemm_bt<0, 0><<<g3, 256, 0, stream>>>(ctx_b, wd_b, nullptr, (void*)out, 4096, 4096, 4096);
}

// Round 2
// 791.152 us; speedup vs baseline: 1.1300x; 1.1300x over previous
//
#include <hip/hip_runtime.h>
#include <hip/hip_bf16.h>
#include <stdint.h>

typedef __attribute__((ext_vector_type(8))) short bf16x8;
typedef __attribute__((ext_vector_type(4))) float f32x4;

#define B_   2
#define SQ_  2048
#define H_   4096
#define NH_  32
#define NG_  2
#define HN_  128
#define QKVO 4608

__device__ __forceinline__ unsigned short f2b(float f) {
    union { float f; uint32_t u; } v; v.f = f;
    uint32_t u = v.u;
    u += 0x7FFFu + ((u >> 16) & 1u);   // round-to-nearest-even
    return (unsigned short)(u >> 16);
}
__device__ __forceinline__ float b2f(unsigned short h) {
    union { uint32_t u; float f; } v; v.u = ((uint32_t)h) << 16;
    return v.f;
}

// ---------------- f32 -> bf16 convert ----------------
__global__ __launch_bounds__(256) void cvt_kernel(const float* __restrict__ in,
                                                  unsigned short* __restrict__ out,
                                                  int n) {
    int i = (blockIdx.x * 256 + threadIdx.x) * 4;
    if (i >= n) return;
    float4 v = *reinterpret_cast<const float4*>(in + i);
    ushort4 o;
    o.x = f2b(v.x); o.y = f2b(v.y); o.z = f2b(v.z); o.w = f2b(v.w);
    *reinterpret_cast<ushort4*>(out + i) = o;
}

// ---------------- m97-structure bf16 GEMM: C = A @ B^T (+bias) ----------------
#define GLD16(gp, lp) \
  __builtin_amdgcn_global_load_lds((const __attribute__((address_space(1))) void*)(gp), \
                                   (__attribute__((address_space(3))) void*)(lp), 16, 0, 0)

template<int OUT_BF16, int HAS_BIAS>
__global__ __launch_bounds__(256) void gemm_bt(const unsigned short* __restrict__ A,
                                               const unsigned short* __restrict__ Bm,
                                               const float* __restrict__ bias,
                                               void* __restrict__ C,
                                               int M, int N, int K) {
    __shared__ unsigned short As[128 * 32];
    __shared__ unsigned short Bs[128 * 32];
    const int tid = threadIdx.x;
    const int wave = tid >> 6, lane = tid & 63;
    const int lr = lane & 15, lg = lane >> 4;
    const int m0 = blockIdx.x * 128, n0 = blockIdx.y * 128;
    const int wr = wave >> 1, wc = wave & 1;

    const int srow = lane >> 2;
    const int skk  = (lane & 3) * 8;

    f32x4 acc[4][4] = {};

    for (int k0 = 0; k0 < K; k0 += 32) {
        __syncthreads();
        #pragma unroll
        for (int c = 0; c < 2; ++c) {
            int ch = c * 4 + wave;
            int row = ch * 16 + srow;
            GLD16(A  + (size_t)(m0 + row) * K + k0 + skk, As + ch * 512);
            GLD16(Bm + (size_t)(n0 + row) * K + k0 + skk, Bs + ch * 512);
        }
        __syncthreads();
        bf16x8 af[4], bf[4];
        #pragma unroll
        for (int i = 0; i < 4; ++i)
            af[i] = *reinterpret_cast<const bf16x8*>(As + (wr * 64 + i * 16 + lr) * 32 + lg * 8);
        #pragma unroll
        for (int j = 0; j < 4; ++j)
            bf[j] = *reinterpret_cast<const bf16x8*>(Bs + (wc * 64 + j * 16 + lr) * 32 + lg * 8);
        #pragma unroll
        for (int i = 0; i < 4; ++i)
            #pragma unroll
            for (int j = 0; j < 4; ++j)
                acc[i][j] = __builtin_amdgcn_mfma_f32_16x16x32_bf16(af[i], bf[j], acc[i][j], 0, 0, 0);
    }

    const int crow0 = m0 + wr * 64;
    const int ccol0 = n0 + wc * 64;
    #pragma unroll
    for (int j = 0; j < 4; ++j) {
        int col = ccol0 + j * 16 + lr;
        float bv = 0.f;
        if (HAS_BIAS) bv = bias[col];
        #pragma unroll
        for (int i = 0; i < 4; ++i) {
            #pragma unroll
            for (int r = 0; r < 4; ++r) {
                int row = crow0 + i * 16 + lg * 4 + r;
                float vv = acc[i][j][r] + bv;
                if (OUT_BF16)
                    reinterpret_cast<unsigned short*>(C)[(size_t)row * N + col] = f2b(vv);
                else
                    reinterpret_cast<float*>(C)[(size_t)row * N + col] = vv;
            }
        }
    }
}

// ---------------- RoPE + GQA scatter (q pre-scaled by log2e/sqrt(128)) ----------------
__global__ __launch_bounds__(256) void rope_scatter(const unsigned short* __restrict__ mixed,
                                                    const float* __restrict__ cache,
                                                    unsigned short* __restrict__ q,
                                                    unsigned short* __restrict__ k,
                                                    unsigned short* __restrict__ v) {
    int idx = blockIdx.x * 256 + threadIdx.x;
    int c = idx & 15;
    int t = idx >> 4;
    int head = t % 36;
    int bs = t / 36;
    int s = bs & 2047;
    int batch = bs >> 11;

    const unsigned short* src = mixed + (size_t)bs * QKVO + head * 128 + c * 8;
    bf16x8 xv = *reinterpret_cast<const bf16x8*>(src);
    float x[8];
    #pragma unroll
    for (int j = 0; j < 8; ++j) x[j] = b2f((unsigned short)xv[j]);

    if (head < 34 && c < 8) {   // rope on first 64 dims, interleaved pairs
        const float* cp = cache + ((size_t)s * 32 + c * 4) * 2;
        #pragma unroll
        for (int jj = 0; jj < 4; ++jj) {
            float co = cp[jj * 2 + 0], si = cp[jj * 2 + 1];
            float x0 = x[2 * jj], x1 = x[2 * jj + 1];
            x[2 * jj]     = x0 * co - x1 * si;
            x[2 * jj + 1] = x1 * co + x0 * si;
        }
    }
    if (head < 32) {            // fold softmax scale*log2e into q
        #pragma unroll
        for (int j = 0; j < 8; ++j) x[j] *= 0.12751743f;   // log2e/sqrt(128)
    }
    bf16x8 ov;
    #pragma unroll
    for (int j = 0; j < 8; ++j) ov[j] = (short)f2b(x[j]);

    unsigned short* dst;
    if (head < 32)
        dst = q + (((size_t)(batch * NH_ + head) * SQ_ + s) * HN_) + c * 8;
    else if (head < 34)
        dst = k + (((size_t)(batch * NG_ + (head - 32)) * SQ_ + s) * HN_) + c * 8;
    else
        dst = v + (((size_t)(batch * NG_ + (head - 34)) * SQ_ + s) * HN_) + c * 8;
    *reinterpret_cast<bf16x8*>(dst) = ov;
}

// ---------------- V transpose: [bg][s][d] -> [bg][d][s] (XOR-swizzled LDS) ----------------
__global__ __launch_bounds__(256) void vtrans_kernel(const unsigned short* __restrict__ v,
                                                     unsigned short* __restrict__ vt) {
    __shared__ __align__(16) unsigned short T[64 * 128];
    const int bg = blockIdx.x >> 5;
    const int st = blockIdx.x & 31;
    const int s0 = st * 64;
    const int tid = threadIdx.x;
    const unsigned short* src = v + (size_t)bg * SQ_ * HN_;
    unsigned short* dst = vt + (size_t)bg * SQ_ * HN_;
    char* Tb = (char*)T;
    #pragma unroll
    for (int it = 0; it < 4; ++it) {
        int idx = it * 256 + tid;
        int r = idx >> 4, c = idx & 15;
        bf16x8 x = *reinterpret_cast<const bf16x8*>(src + (size_t)(s0 + r) * HN_ + c * 8);
        int byt = (r * 256 + c * 16) ^ (((r >> 3) & 7) << 4);
        *reinterpret_cast<bf16x8*>(Tb + byt) = x;
    }
    __syncthreads();
    #pragma unroll
    for (int it = 0; it < 4; ++it) {
        int idx = it * 256 + tid;
        int d = idx >> 3, sc = idx & 7;
        bf16x8 o;
        #pragma unroll
        for (int j = 0; j < 8; ++j) {
            int s = sc * 8 + j;
            int byt = (s * 256 + d * 2) ^ (((s >> 3) & 7) << 4);
            o[j] = *reinterpret_cast<const unsigned short*>(Tb + byt);
        }
        *reinterpret_cast<bf16x8*>(dst + (size_t)d * SQ_ + s0 + sc * 8) = o;
    }
}

// ---------------- causal GQA flash attention (no K/V staging, no barriers) ----------------
// grid (b*NH, sq/128); 256 threads = 4 waves; wave owns 32 q-rows.
// Q pre-scaled so P = exp2(s - m). K global [key][d]; V global transposed [d][key].
__global__ __launch_bounds__(256) void attn_kernel(const unsigned short* __restrict__ Q,
                                                   const unsigned short* __restrict__ K,
                                                   const unsigned short* __restrict__ VT,
                                                   unsigned short* __restrict__ ctx) {
    __shared__ __align__(16) unsigned short Pl[4][32][72];   // per-wave P round-trip

    const int bh = blockIdx.x;
    const int qt = blockIdx.y;
    const int batch = bh >> 5, h = bh & 31, g = h >> 4;
    const int tid = threadIdx.x, wave = tid >> 6, lane = tid & 63;
    const int lr = lane & 15, lg = lane >> 4;
    const int q0w = qt * 128 + wave * 32;

    const unsigned short* Qp = Q + ((size_t)(batch * NH_ + h) * SQ_ + q0w) * HN_;
    const unsigned short* Kp = K + (size_t)(batch * NG_ + g) * SQ_ * HN_;
    const unsigned short* Vp = VT + (size_t)(batch * NG_ + g) * SQ_ * HN_;

    bf16x8 qf[2][4];
    #pragma unroll
    for (int mi = 0; mi < 2; ++mi)
        #pragma unroll
        for (int kd = 0; kd < 4; ++kd)
            qf[mi][kd] = *reinterpret_cast<const bf16x8*>(Qp + (size_t)(mi * 16 + lr) * HN_ + kd * 32 + lg * 8);

    f32x4 ctxa[2][8] = {};
    float mrow[2][4], lsump[2][4];
    #pragma unroll
    for (int mi = 0; mi < 2; ++mi)
        #pragma unroll
        for (int r = 0; r < 4; ++r) { mrow[mi][r] = -1e30f; lsump[mi][r] = 0.f; }

    const int nkt = (q0w + 95) >> 6;   // tiles covering keys 0..q0w+31
    #pragma unroll 1
    for (int kt = 0; kt < nkt; ++kt) {
        const int kbase = kt * 64;

        // K fragments direct from global (L2-resident): 16 x b128
        bf16x8 kfr[4][4];
        #pragma unroll
        for (int kf = 0; kf < 4; ++kf)
            #pragma unroll
            for (int kd = 0; kd < 4; ++kd)
                kfr[kf][kd] = *reinterpret_cast<const bf16x8*>(Kp + (size_t)(kbase + kf * 16 + lr) * HN_ + kd * 32 + lg * 8);

        f32x4 s[2][4] = {};
        __builtin_amdgcn_s_setprio(1);
        #pragma unroll
        for (int kf = 0; kf < 4; ++kf)
            #pragma unroll
            for (int kd = 0; kd < 4; ++kd)
                #pragma unroll
                for (int mi = 0; mi < 2; ++mi)
                    s[mi][kf] = __builtin_amdgcn_mfma_f32_16x16x32_bf16(qf[mi][kd], kfr[kf][kd], s[mi][kf], 0, 0, 0);
        __builtin_amdgcn_s_setprio(0);

        // V^T fragments direct from global: 16 x b128 (overlap with softmax)
        bf16x8 vfr[2][8];
        #pragma unroll
        for (int ks = 0; ks < 2; ++ks)
            #pragma unroll
            for (int df = 0; df < 8; ++df)
                vfr[ks][df] = *reinterpret_cast<const bf16x8*>(Vp + (size_t)(df * 16 + lr) * SQ_ + kbase + ks * 32 + lg * 8);

        const bool maskTile = (kbase + 63 > q0w);   // wave-uniform
        if (maskTile) {
            #pragma unroll
            for (int mi = 0; mi < 2; ++mi)
                #pragma unroll
                for (int kf = 0; kf < 4; ++kf)
                    #pragma unroll
                    for (int r = 0; r < 4; ++r) {
                        int qrow = q0w + mi * 16 + lg * 4 + r;
                        int kcol = kbase + kf * 16 + lr;
                        if (kcol > qrow) s[mi][kf][r] = -1e30f;
                    }
        }

        // defer-max: local row max + threshold check (exp2 domain, THR=8)
        float pmaxl[2][4];
        float worst = -1e30f;
        #pragma unroll
        for (int mi = 0; mi < 2; ++mi)
            #pragma unroll
            for (int r = 0; r < 4; ++r) {
                float pm = fmaxf(fmaxf(s[mi][0][r], s[mi][1][r]), fmaxf(s[mi][2][r], s[mi][3][r]));
                pmaxl[mi][r] = pm;
                worst = fmaxf(worst, pm - mrow[mi][r]);
            }
        if (maskTile || __any(worst > 8.0f)) {
            #pragma unroll
            for (int mi = 0; mi < 2; ++mi)
                #pragma unroll
                for (int r = 0; r < 4; ++r) {
                    float pm = pmaxl[mi][r];
                    pm = fmaxf(pm, __shfl_xor(pm, 1));
                    pm = fmaxf(pm, __shfl_xor(pm, 2));
                    pm = fmaxf(pm, __shfl_xor(pm, 4));
                    pm = fmaxf(pm, __shfl_xor(pm, 8));
                    float mnew = fmaxf(mrow[mi][r], pm);
                    float resc = exp2f(mrow[mi][r] - mnew);
                    mrow[mi][r] = mnew;
                    lsump[mi][r] *= resc;
                    #pragma unroll
                    for (int df = 0; df < 8; ++df)
                        ctxa[mi][df][r] *= resc;
                }
        }

        // P = exp2(s - m), per-lane partial lsum, store to wave-local LDS
        #pragma unroll
        for (int mi = 0; mi < 2; ++mi)
            #pragma unroll
            for (int r = 0; r < 4; ++r) {
                float m = mrow[mi][r];
                #pragma unroll
                for (int kf = 0; kf < 4; ++kf) {
                    float p = exp2f(s[mi][kf][r] - m);
                    lsump[mi][r] += p;
                    Pl[wave][mi * 16 + lg * 4 + r][kf * 16 + lr] = f2b(p);
                }
            }
        asm volatile("s_waitcnt lgkmcnt(0)" ::: "memory");
        __builtin_amdgcn_sched_barrier(0);

        // P fragments (A-layout) from LDS
        bf16x8 pf[2][2];
        #pragma unroll
        for (int ks = 0; ks < 2; ++ks)
            #pragma unroll
            for (int mi = 0; mi < 2; ++mi)
                pf[ks][mi] = *reinterpret_cast<const bf16x8*>(&Pl[wave][mi * 16 + lr][ks * 32 + lg * 8]);

        __builtin_amdgcn_s_setprio(1);
        #pragma unroll
        for (int ks = 0; ks < 2; ++ks)
            #pragma unroll
            for (int df = 0; df < 8; ++df)
                #pragma unroll
                for (int mi = 0; mi < 2; ++mi)
                    ctxa[mi][df] = __builtin_amdgcn_mfma_f32_16x16x32_bf16(pf[ks][mi], vfr[ks][df], ctxa[mi][df], 0, 0, 0);
        __builtin_amdgcn_s_setprio(0);
    }

    // finalize: reduce per-lane partial sums across the 16-lane row group, write bf16
    #pragma unroll
    for (int mi = 0; mi < 2; ++mi) {
        #pragma unroll
        for (int r = 0; r < 4; ++r) {
            float ls = lsump[mi][r];
            ls += __shfl_xor(ls, 1);
            ls += __shfl_xor(ls, 2);
            ls += __shfl_xor(ls, 4);
            ls += __shfl_xor(ls, 8);
            float inv = 1.f / ls;
            int row = batch * SQ_ + q0w + mi * 16 + lg * 4 + r;
            #pragma unroll
            for (int df = 0; df < 8; ++df) {
                int col = h * HN_ + df * 16 + lr;
                ctx[(size_t)row * (NH_ * HN_) + col] = f2b(ctxa[mi][df][r] * inv);
            }
        }
    }
}

extern "C" void kernel_launch(void* const* d_in, const int* in_sizes, int n_in,
                              void* d_out, int out_size, void* d_ws, size_t ws_size,
                              hipStream_t stream) {
    const float* hs      = (const float*)d_in[0];
    const float* cache   = (const float*)d_in[1];
    const float* w_qkv   = (const float*)d_in[2];
    const float* b_qkv   = (const float*)d_in[3];
    const float* w_dense = (const float*)d_in[4];
    float* out = (float*)d_out;

    char* p = (char*)d_ws;
    unsigned short* hs_b    = (unsigned short*)p; p += (size_t)16777216 * 2;  // [4096][4096]
    unsigned short* wqkv_b  = (unsigned short*)p; p += (size_t)18874368 * 2;  // [4608][4096]
    unsigned short* wd_b    = (unsigned short*)p; p += (size_t)16777216 * 2;  // [4096][4096]
    unsigned short* mixed_b = (unsigned short*)p; p += (size_t)18874368 * 2;  // [4096][4608]
    unsigned short* q_b     = (unsigned short*)p; p += (size_t)16777216 * 2;  // [2][32][2048][128]
    unsigned short* k_b     = (unsigned short*)p; p += (size_t)1048576 * 2;   // [2][2][2048][128]
    unsigned short* v_b     = (unsigned short*)p; p += (size_t)1048576 * 2;   // [2][2][2048][128]
    unsigned short* vt_b    = (unsigned short*)p; p += (size_t)1048576 * 2;   // [2][2][128][2048]
    unsigned short* ctx_b   = (unsigned short*)p; p += (size_t)16777216 * 2;  // [4096][4096]

    cvt_kernel<<<16384, 256, 0, stream>>>(hs, hs_b, 16777216);
    cvt_kernel<<<18432, 256, 0, stream>>>(w_qkv, wqkv_b, 18874368);
    cvt_kernel<<<16384, 256, 0, stream>>>(w_dense, wd_b, 16777216);

    dim3 g1(32, 36);
    gemm_bt<1, 1><<<g1, 256, 0, stream>>>(hs_b, wqkv_b, b_qkv, (void*)mixed_b, 4096, 4608, 4096);

    rope_scatter<<<9216, 256, 0, stream>>>(mixed_b, cache, q_b, k_b, v_b);
    vtrans_kernel<<<128, 256, 0, stream>>>(v_b, vt_b);

    dim3 g2(64, 16);
    attn_kernel<<<g2, 256, 0, stream>>>(q_b, k_b, vt_b, ctx_b);

    dim3 g3(32, 32);
    gemm_bt<0, 0><<<g3, 256, 0, stream>>>(ctx_b, wd_b, nullptr, (void*)out, 4096, 4096, 4096);
}